// Round 5
// baseline (278.865 us; speedup 1.0000x reference)
//
#include <hip/hip_runtime.h>
#include <cstdint>
#include <cstddef>

// ---------------------------------------------------------------------------
// COAMultiHeadAttention on gfx950: B=2, T=2048, D=1024, H=16, HD=64.
// detect -> cvt(bf16, merged) -> mask prepass -> merged QKV GEMM
//   (64x128 tile, 3-buffer counted-vmcnt pipeline, V-transpose fused in
//    epilogue) -> flash attn (32x32 swapped-QK^T, in-register softmax,
//    3-buffer counted-vmcnt, 3 blocks/CU) -> out GEMM.
// ---------------------------------------------------------------------------

using frag8  = __attribute__((ext_vector_type(8))) short;   // 8 x bf16
using f32x4  = __attribute__((ext_vector_type(4))) float;
using f32x16 = __attribute__((ext_vector_type(16))) float;  // 32x32 MFMA accum
using int4v  = __attribute__((ext_vector_type(4))) int;     // 16B vector

#define MFMA16(a,b,c) __builtin_amdgcn_mfma_f32_16x16x32_bf16((a),(b),(c),0,0,0)
#define MFMA32(a,b,c) __builtin_amdgcn_mfma_f32_32x32x16_bf16((a),(b),(c),0,0,0)

#define T_SEQ 2048
#define D_MOD 1024
#define QSCALE 0.18033688011112042f   // 0.125 * log2(e): fold attn scale + exp2 domain into Q

__device__ __forceinline__ float bf2f(unsigned short s) {
    unsigned u = ((unsigned)s) << 16;
    return __builtin_bit_cast(float, u);
}
__device__ __forceinline__ short f2bf(float f) {
    unsigned u = __builtin_bit_cast(unsigned, f);
    u += 0x7fffu + ((u >> 16) & 1u);   // RNE
    return (short)(u >> 16);
}

// async global->LDS, 16B per lane. LDS dest = wave-uniform base + lane*16.
__device__ __forceinline__ void gload16(const void* g, void* l) {
    auto gp = (const __attribute__((address_space(1))) char*)(uintptr_t)(g);
    auto lp = (__attribute__((address_space(3))) char*)(uintptr_t)(l);
    __builtin_amdgcn_global_load_lds(
        (const __attribute__((address_space(1))) void*)gp,
        (__attribute__((address_space(3))) void*)lp, 16, 0, 0);
}

#define VMCNT(n) asm volatile("s_waitcnt vmcnt(" #n ")" ::: "memory")
#define BARRIER() do { __builtin_amdgcn_s_barrier(); __builtin_amdgcn_sched_barrier(0); } while (0)

// hardware 2^x
__device__ __forceinline__ float exp2_hw(float x) {
    float r;
    asm("v_exp_f32 %0, %1" : "=v"(r) : "v"(x));
    return r;
}
// pack 2 f32 -> bf16x2 in one inst: D.lo = cvt(a), D.hi = cvt(b)
__device__ __forceinline__ unsigned cvtpk(float a, float b) {
    unsigned r;
    asm("v_cvt_pk_bf16_f32 %0, %1, %2" : "=v"(r) : "v"(a), "v"(b));
    return r;
}

// Cross-half exchange building PV A-frags (direction-unambiguous, via shfl).
__device__ __forceinline__ void xhalf(unsigned& a0, unsigned& a1,
                                      unsigned& a2, unsigned& a3, const int hi) {
    const unsigned sA = hi ? a0 : a2;
    const unsigned sB = hi ? a1 : a3;
    const unsigned tA = __shfl_xor(sA, 32, 64);
    const unsigned tB = __shfl_xor(sB, 32, 64);
    a0 = hi ? tA : a0;
    a1 = hi ? tB : a1;
    a2 = hi ? a2 : tA;
    a3 = hi ? a3 : tB;
}

// ---------------------------------------------------------------------------
// Dtype detection: f32 data read as shorts shows large bf16 exponent fields.
// ---------------------------------------------------------------------------
__global__ void detect_dtype(const unsigned short* __restrict__ q, int* __restrict__ flag) {
    if (threadIdx.x == 0) {
        int f = 0;
        for (int i = 0; i < 256; ++i) {
            const int e = (q[i] >> 7) & 0xFF;
            f |= (e >= 0xC0) ? 1 : 0;
        }
        *flag = f;   // 1 => external floats are f32, 0 => bf16
    }
}

// ---------------------------------------------------------------------------
// f32 -> bf16 conversion, all 7 tensors in one launch (runs only when f32).
// ---------------------------------------------------------------------------
__device__ __forceinline__ void cvt8(unsigned short* dst, const float* src) {
    float4 lo = *(const float4*)src;
    float4 hi = *(const float4*)(src + 4);
    union { int4v v; unsigned short s[8]; } pk;
    pk.s[0] = (unsigned short)f2bf(lo.x); pk.s[1] = (unsigned short)f2bf(lo.y);
    pk.s[2] = (unsigned short)f2bf(lo.z); pk.s[3] = (unsigned short)f2bf(lo.w);
    pk.s[4] = (unsigned short)f2bf(hi.x); pk.s[5] = (unsigned short)f2bf(hi.y);
    pk.s[6] = (unsigned short)f2bf(hi.z); pk.s[7] = (unsigned short)f2bf(hi.w);
    *(int4v*)dst = pk.v;
}

__global__ __launch_bounds__(256) void cvt_all(
    const float* __restrict__ q, const float* __restrict__ k, const float* __restrict__ v,
    const float* __restrict__ wq, const float* __restrict__ wk,
    const float* __restrict__ wv, const float* __restrict__ wo,
    unsigned short* __restrict__ xq, unsigned short* __restrict__ xk,
    unsigned short* __restrict__ xv,
    unsigned short* __restrict__ owq, unsigned short* __restrict__ owk,
    unsigned short* __restrict__ owv, unsigned short* __restrict__ owo,
    const int* __restrict__ dflag)
{
    if (dflag[0] == 0) return;
    const int y = blockIdx.y;
    if (y >= 3 && blockIdx.x >= 512) return;   // weights are 1M elems (512 blocks)
    const float* src;
    unsigned short* dst;
    switch (y) {
        case 0: src = q;  dst = xq;  break;
        case 1: src = k;  dst = xk;  break;
        case 2: src = v;  dst = xv;  break;
        case 3: src = wq; dst = owq; break;
        case 4: src = wk; dst = owk; break;
        case 5: src = wv; dst = owv; break;
        default: src = wo; dst = owo; break;
    }
    const size_t i = ((size_t)blockIdx.x * 256 + threadIdx.x) * 8;
    cvt8(dst + i, src + i);
}

// ---------------------------------------------------------------------------
// GEMM body: Y tile at (m0,n0) = X[M,K] @ W[N,K]^T + bias.
// Tile 64(M) x 128(N) x BK=64; 4 waves as 2Mx2N, each 32x64 (2x4 MFMA tiles).
// 3 LDS buffers (72KB, 2 blocks/CU) + counted vmcnt: stage tile t+2 at top of
// iter t; s_waitcnt vmcnt(6) only forces stage t+1 complete -> t+2's loads
// stay in flight across the barrier (T4). vt_mode: write V transposed
// (fused vtrans) via LDS transpose instead of the normal row-major store.
// ---------------------------------------------------------------------------
__device__ __forceinline__ void gemm_body(
    const unsigned short* __restrict__ X, const unsigned short* __restrict__ W,
    const void* __restrict__ bias, void* __restrict__ Y,
    const int N, const int K, const int isf32, const int y_f32, const float oscale,
    const int m0, const int n0, const int vt_mode, unsigned short* __restrict__ Vt)
{
    __shared__ short sA[3][64][64];     // 24 KB
    __shared__ short sB[3][128][64];    // 48 KB

    const int tid = threadIdx.x;
    const int w   = tid >> 6;
    const int l   = tid & 63;
    const int g   = l >> 4;
    const int r   = l & 15;
    const int rx  = r & 7;
    const int wm  = (w >> 1) * 32;
    const int wn  = (w & 1) * 64;
    const int lr  = l >> 3;           // 0..7: row within 8-row DMA chunk
    const int lc  = (l & 7) ^ lr;     // pre-swizzled source chunk (row&7 key)

    const unsigned short* xsrc = X + (size_t)(m0 + w * 16 + lr) * K + lc * 8;
    const unsigned short* wsrc = W + (size_t)(n0 + w * 32 + lr) * K + lc * 8;

    f32x4 acc[2][4] = {};

    // 6 gload16 per wave per stage
#define STAGE_AB(buf, kofs)                                                       \
    {                                                                             \
        gload16(xsrc + (size_t)0 * K  + (kofs), &sA[buf][w * 16][0]);             \
        gload16(xsrc + (size_t)8 * K  + (kofs), &sA[buf][w * 16 + 8][0]);         \
        gload16(wsrc + (size_t)0 * K  + (kofs), &sB[buf][w * 32][0]);             \
        gload16(wsrc + (size_t)8 * K  + (kofs), &sB[buf][w * 32 + 8][0]);         \
        gload16(wsrc + (size_t)16 * K + (kofs), &sB[buf][w * 32 + 16][0]);        \
        gload16(wsrc + (size_t)24 * K + (kofs), &sB[buf][w * 32 + 24][0]);        \
    }

    STAGE_AB(0, 0);
    STAGE_AB(1, 64);
    VMCNT(6);            // buffer 0 complete; stage 1 may remain in flight
    BARRIER();

    int rd = 0;
    for (int k0 = 0; k0 < K; k0 += 64) {
        const bool more = (k0 + 128 < K);
        if (more) {
            const int wr = (rd == 0) ? 2 : rd - 1;   // (t+2)%3
            STAGE_AB(wr, k0 + 128);
        }
#pragma unroll
        for (int ks = 0; ks < 2; ++ks) {
            frag8 af[2], bfr[4];
#pragma unroll
            for (int mt = 0; mt < 2; ++mt)
                af[mt] = *(const frag8*)&sA[rd][wm + mt * 16 + r][((ks * 4 + g) ^ rx) * 8];
#pragma unroll
            for (int nt = 0; nt < 4; ++nt)
                bfr[nt] = *(const frag8*)&sB[rd][wn + nt * 16 + r][((ks * 4 + g) ^ rx) * 8];
            __builtin_amdgcn_s_setprio(1);
#pragma unroll
            for (int mt = 0; mt < 2; ++mt)
#pragma unroll
                for (int nt = 0; nt < 4; ++nt)
                    acc[mt][nt] = MFMA16(af[mt], bfr[nt], acc[mt][nt]);
            __builtin_amdgcn_s_setprio(0);
        }
        if (more) { VMCNT(6); } else { VMCNT(0); }
        BARRIER();
        rd = (rd == 2) ? 0 : rd + 1;
    }
#undef STAGE_AB

    if (!vt_mode) {
#pragma unroll
        for (int nt = 0; nt < 4; ++nt) {
            const int n = n0 + wn + nt * 16 + r;
            const float bv = isf32 ? ((const float*)bias)[n]
                                   : bf2f(((const unsigned short*)bias)[n]);
#pragma unroll
            for (int mt = 0; mt < 2; ++mt) {
#pragma unroll
                for (int reg = 0; reg < 4; ++reg) {
                    const int m = m0 + wm + mt * 16 + g * 4 + reg;
                    const float val = (acc[mt][nt][reg] + bv) * oscale;
                    if (y_f32)
                        ((float*)Y)[(size_t)m * N + n] = val;
                    else
                        ((unsigned short*)Y)[(size_t)m * N + n] = (unsigned short)f2bf(val);
                }
            }
        }
    } else {
        // fused V transpose: Vt[(b*16+h)*64 + d][t], b=m>>11, t=m&2047, h*64+d=n.
        short (*sT)[64] = (short(*)[64])(&sA[0][0][0]);   // [128 n][64 m], 16KB
#pragma unroll
        for (int nt = 0; nt < 4; ++nt) {
            const int n = n0 + wn + nt * 16 + r;
            const float bv = isf32 ? ((const float*)bias)[n]
                                   : bf2f(((const unsigned short*)bias)[n]);
#pragma unroll
            for (int mt = 0; mt < 2; ++mt)
#pragma unroll
                for (int reg = 0; reg < 4; ++reg)
                    sT[wn + nt * 16 + r][wm + mt * 16 + g * 4 + reg] =
                        f2bf(acc[mt][nt][reg] + bv);
        }
        __syncthreads();
        const int row = tid >> 1, half = tid & 1;
        const int gn = n0 + row;
        const size_t vr = (size_t)(m0 >> 11) * 1024 + (size_t)(gn >> 6) * 64 + (gn & 63);
        unsigned short* dst = Vt + vr * T_SEQ + (m0 & 2047) + half * 32;
        const short* srcp = &sT[row][half * 32];
#pragma unroll
        for (int j = 0; j < 4; ++j)
            *(int4v*)(dst + j * 8) = *(const int4v*)(srcp + j * 8);
    }
}

// merged Q/K/V projection: blockIdx.z selects the tensor
__global__ __launch_bounds__(256) void gemm_qkv(
    const void* q, const unsigned short* qc, const void* k, const unsigned short* kc,
    const void* v, const unsigned short* vc,
    const void* wq, const unsigned short* wqc, const void* wk, const unsigned short* wkc,
    const void* wv, const unsigned short* wvc,
    const void* bq, const void* bk, const void* bv,
    unsigned short* Qp, unsigned short* Kp, unsigned short* Vt,
    const int* __restrict__ dflag)
{
    const int isf32 = dflag[0];
    const int z = blockIdx.z;
    const unsigned short* X;
    const unsigned short* W;
    const void* B;
    unsigned short* Y;
    float sc;
    if (z == 0) {
        X = isf32 ? qc : (const unsigned short*)q;
        W = isf32 ? wqc : (const unsigned short*)wq;
        B = bq; Y = Qp; sc = QSCALE;
    } else if (z == 1) {
        X = isf32 ? kc : (const unsigned short*)k;
        W = isf32 ? wkc : (const unsigned short*)wk;
        B = bk; Y = Kp; sc = 1.0f;
    } else {
        X = isf32 ? vc : (const unsigned short*)v;
        W = isf32 ? wvc : (const unsigned short*)wv;
        B = bv; Y = nullptr; sc = 1.0f;
    }
    gemm_body(X, W, B, Y, D_MOD, D_MOD, isf32, 0, sc,
              blockIdx.y * 64, blockIdx.x * 128, z == 2, Vt);
}

__global__ __launch_bounds__(256) void gemm_out(
    const unsigned short* __restrict__ att, const void* wo, const unsigned short* woc,
    const void* bo, void* out, const int* __restrict__ dflag)
{
    const int isf32 = dflag[0];
    const unsigned short* W = isf32 ? woc : (const unsigned short*)wo;
    gemm_body(att, W, bo, out, D_MOD, D_MOD, isf32, isf32, 1.0f,
              blockIdx.y * 64, blockIdx.x * 128, 0, nullptr);
}

// ---------------------------------------------------------------------------
// Mask prepass: flags[b][qt][kt] = 1 iff any zero in the 64x64 mask tile.
// ---------------------------------------------------------------------------
__global__ __launch_bounds__(256) void mask_tiles(const int* __restrict__ mask,
                                                  int* __restrict__ flags)
{
    __shared__ int f;
    const int tid = threadIdx.x;
    if (tid == 0) f = 0;
    __syncthreads();
    const int b = blockIdx.z, qt = blockIdx.y, kt = blockIdx.x;
    const int* base = mask + (size_t)b * T_SEQ * T_SEQ
                    + (size_t)(qt * 64 + (tid >> 2)) * T_SEQ + kt * 64 + (tid & 3) * 16;
    int any = 0;
#pragma unroll
    for (int j = 0; j < 4; ++j) {
        int4v v = *(const int4v*)(base + j * 4);
        any |= (v.x == 0) | (v.y == 0) | (v.z == 0) | (v.w == 0);
    }
    if (any) f = 1;
    __syncthreads();
    if (tid == 0) flags[((size_t)b * 32 + qt) * 32 + kt] = f;
}

// ---------------------------------------------------------------------------
// Flash attention, 32x32 swapped-QK^T. Block = 4 waves x 32 q = 128 q;
// grid (16,16,2) = 512 blocks. 3-buffer counted-vmcnt K/V pipeline
// (48KB LDS -> 3 blocks/CU); per-block mask bitmask hoisted pre-loop.
// ---------------------------------------------------------------------------
__global__ __launch_bounds__(256) void flash_attn(
    const unsigned short* __restrict__ Qp, const unsigned short* __restrict__ Kp,
    const unsigned short* __restrict__ Vt, const int* __restrict__ mask,
    const int* __restrict__ flags, unsigned short* __restrict__ att)
{
    __shared__ short sK[3][64][64];
    __shared__ short sV[3][64][64];     // [buf][d][k]

    const int tid = threadIdx.x;
    const int w   = tid >> 6;
    const int l   = tid & 63;
    const int lq  = l & 31;             // frag row / S column (this lane's q)
    const int hi  = l >> 5;
    const int lx  = lq & 7;             // read-side swizzle key
    const int b = blockIdx.z, h = blockIdx.y;
    const int q0 = blockIdx.x * 128;
    const int qw = q0 + w * 32;
    const int r0 = tid >> 3;            // staging row 0..31
    const int c0 = tid & 7;
    const int sc = c0 ^ (r0 & 7);       // pre-swizzled source chunk

    const size_t qkbase = (size_t)b * T_SEQ * D_MOD + (size_t)h * 64;
    const unsigned short* ksrc = Kp + qkbase + (size_t)r0 * D_MOD + sc * 8;
    const unsigned short* vsrc = Vt + ((size_t)((b * 16 + h) * 64) + r0) * T_SEQ + sc * 8;

    // 4 gload16 per wave per stage
#define STAGE_KV(buf, ktv)                                                        \
    {                                                                             \
        gload16(ksrc + (size_t)(ktv) * D_MOD,        &sK[buf][r0][c0 * 8]);       \
        gload16(ksrc + (size_t)((ktv) + 32) * D_MOD, &sK[buf][r0 + 32][c0 * 8]);  \
        gload16(vsrc + (ktv),                        &sV[buf][r0][c0 * 8]);       \
        gload16(vsrc + (size_t)32 * T_SEQ + (ktv),   &sV[buf][r0 + 32][c0 * 8]);  \
    }

    // mask-tile bitmask for this (b, q-block): bit t = tile kt=64*t has zeros
    const int* tfl = flags + ((size_t)b * 32 + (qw >> 6)) * 32;
    unsigned fmask = 0;
#pragma unroll
    for (int t = 0; t < 32; ++t) fmask |= (tfl[t] ? 1u : 0u) << t;

    // Q fragments straight from global (L2-hot), B-layout: row lq, hd-slice
    frag8 qf[4];
    {
        const unsigned short* qrow = Qp + qkbase + (size_t)(qw + lq) * D_MOD + hi * 8;
#pragma unroll
        for (int ks = 0; ks < 4; ++ks)
            qf[ks] = *(const frag8*)(qrow + ks * 16);
    }

    STAGE_KV(0, 0);
    STAGE_KV(1, 64);
    VMCNT(4);            // buffer 0 complete; stage 1 may remain in flight
    BARRIER();

    float run_m = -1e30f, run_l = 0.f;
    f32x16 accO0 = {}, accO1 = {};

    const int* mq = mask + ((size_t)b * T_SEQ + qw + lq) * T_SEQ;

    int rd = 0;
    for (int kt = 0; kt < T_SEQ; kt += 64) {
        const bool more = (kt + 128 < T_SEQ);
        if (more) {
            const int wr = (rd == 0) ? 2 : rd - 1;   // (t+2)%3
            STAGE_KV(wr, kt + 128);
        }

        // ---- S^T = K Q^T : C[k][q], lane holds 32 S values of one q-row ----
        f32x16 s0 = {}, s1 = {};
        __builtin_amdgcn_s_setprio(1);
#pragma unroll
        for (int ks = 0; ks < 4; ++ks) {
            const int ch = ((ks * 2 + hi) ^ lx) * 8;
            frag8 k0 = *(const frag8*)&sK[rd][lq][ch];
            frag8 k1 = *(const frag8*)&sK[rd][32 + lq][ch];
            s0 = MFMA32(k0, qf[ks], s0);
            s1 = MFMA32(k1, qf[ks], s1);
        }
        __builtin_amdgcn_s_setprio(0);

        // ---- mask (slow path only) ----
        if (fmask & (1u << (kt >> 6))) {
            const int* m0p = mq + kt;
#pragma unroll
            for (int r = 0; r < 16; ++r) {
                const int kof = (r & 3) + 8 * (r >> 2) + 4 * hi;
                if (m0p[kof] == 0)      s0[r] = -1e30f;
                if (m0p[32 + kof] == 0) s1[r] = -1e30f;
            }
        }

        // ---- tile max (in-lane tree + one cross-half exchange) ----
        float tm = s0[0];
#pragma unroll
        for (int r = 1; r < 16; ++r) tm = fmaxf(tm, s0[r]);
#pragma unroll
        for (int r = 0; r < 16; ++r) tm = fmaxf(tm, s1[r]);
        tm = fmaxf(tm, __shfl_xor(tm, 32, 64));

        // ---- defer-max rescale (rare after first tile) ----
        if (__any(tm > run_m + 8.0f)) {
            const float nm = fmaxf(run_m, tm);
            const float al = exp2_hw(run_m - nm);
            run_m = nm;
            run_l *= al;
            float alr[16];
#pragma unroll
            for (int r = 0; r < 16; ++r)
                alr[r] = __shfl(al, (r & 3) + 8 * (r >> 2) + 4 * hi, 64);
#pragma unroll
            for (int r = 0; r < 16; ++r) { accO0[r] *= alr[r]; accO1[r] *= alr[r]; }
        }

        // ---- exp2 + row sum ----
        float a0 = 0.f, a1 = 0.f, a2 = 0.f, a3 = 0.f;
#pragma unroll
        for (int r = 0; r < 16; r += 4) {
            s0[r]     = exp2_hw(s0[r]     - run_m);
            s0[r + 1] = exp2_hw(s0[r + 1] - run_m);
            s0[r + 2] = exp2_hw(s0[r + 2] - run_m);
            s0[r + 3] = exp2_hw(s0[r + 3] - run_m);
            s1[r]     = exp2_hw(s1[r]     - run_m);
            s1[r + 1] = exp2_hw(s1[r + 1] - run_m);
            s1[r + 2] = exp2_hw(s1[r + 2] - run_m);
            s1[r + 3] = exp2_hw(s1[r + 3] - run_m);
            a0 += s0[r]     + s1[r];
            a1 += s0[r + 1] + s1[r + 1];
            a2 += s0[r + 2] + s1[r + 2];
            a3 += s0[r + 3] + s1[r + 3];
        }
        float rs = (a0 + a1) + (a2 + a3);
        rs += __shfl_xor(rs, 32, 64);
        run_l += rs;

        // ---- P -> PV A-frags: cvt_pk pairs + cross-half shfl exchange ----
        union PU { frag8 f; unsigned u[4]; };
        PU pu0, pu1, pu2, pu3;
        pu0.u[0] = cvtpk(s0[0],  s0[1]);  pu0.u[1] = cvtpk(s0[2],  s0[3]);
        pu0.u[2] = cvtpk(s0[4],  s0[5]);  pu0.u[3] = cvtpk(s0[6],  s0[7]);
        pu1.u[0] = cvtpk(s0[8],  s0[9]);  pu1.u[1] = cvtpk(s0[10], s0[11]);
        pu1.u[2] = cvtpk(s0[12], s0[13]); pu1.u[3] = cvtpk(s0[14], s0[15]);
        pu2.u[0] = cvtpk(s1[0],  s1[1]);  pu2.u[1] = cvtpk(s1[2],  s1[3]);
        pu2.u[2] = cvtpk(s1[4],  s1[5]);  pu2.u[3] = cvtpk(s1[6],  s1[7]);
        pu3.u[0] = cvtpk(s1[8],  s1[9]);  pu3.u[1] = cvtpk(s1[10], s1[11]);
        pu3.u[2] = cvtpk(s1[12], s1[13]); pu3.u[3] = cvtpk(s1[14], s1[15]);
        xhalf(pu0.u[0], pu0.u[1], pu0.u[2], pu0.u[3], hi);
        xhalf(pu1.u[0], pu1.u[1], pu1.u[2], pu1.u[3], hi);
        xhalf(pu2.u[0], pu2.u[1], pu2.u[2], pu2.u[3], hi);
        xhalf(pu3.u[0], pu3.u[1], pu3.u[2], pu3.u[3], hi);
        frag8 pa[4] = { pu0.f, pu1.f, pu2.f, pu3.f };

        // ---- O += P V ----
        __builtin_amdgcn_s_setprio(1);
#pragma unroll
        for (int ks = 0; ks < 4; ++ks) {
            const int ch = ((ks * 2 + hi) ^ lx) * 8;
            frag8 v0 = *(const frag8*)&sV[rd][lq][ch];
            frag8 v1 = *(const frag8*)&sV[rd][32 + lq][ch];
            accO0 = MFMA32(pa[ks], v0, accO0);
            accO1 = MFMA32(pa[ks], v1, accO1);
        }
        __builtin_amdgcn_s_setprio(0);

        if (more) { VMCNT(4); } else { VMCNT(0); }
        BARRIER();
        rd = (rd == 2) ? 0 : rd + 1;
    }

    // ---- epilogue: O / l, gather per-row 1/l across lanes ----
    const float rinv = 1.0f / run_l;
    float rr[16];
#pragma unroll
    for (int r = 0; r < 16; ++r)
        rr[r] = __shfl(rinv, (r & 3) + 8 * (r >> 2) + 4 * hi, 64);
#pragma unroll
    for (int r = 0; r < 16; ++r) {
        const int qq = qw + (r & 3) + 8 * (r >> 2) + 4 * hi;
        unsigned short* orow = att + ((size_t)b * T_SEQ + qq) * D_MOD + h * 64 + lq;
        orow[0]  = (unsigned short)f2bf(accO0[r] * rr[r]);
        orow[32] = (unsigned short)f2bf(accO1[r] * rr[r]);
    }
#undef STAGE_KV
}

// ---------------------------------------------------------------------------
extern "C" void kernel_launch(void* const* d_in, const int* in_sizes, int n_in,
                              void* d_out, int out_size, void* d_ws, size_t ws_size,
                              hipStream_t stream) {
    const void* query = d_in[0];
    const void* key   = d_in[1];
    const void* value = d_in[2];
    const int*  mask  = (const int*)d_in[3];
    const void* wq = d_in[4];
    const void* bq = d_in[5];
    const void* wk = d_in[6];
    const void* bk = d_in[7];
    const void* wv = d_in[8];
    const void* bv = d_in[9];
    const void* wo = d_in[10];
    const void* bo = d_in[11];

    const int Mtot = 2 * T_SEQ;              // 4096
    const size_t MD = (size_t)Mtot * D_MOD;  // 4M elems
    const size_t WW = (size_t)D_MOD * D_MOD; // 1M elems

    unsigned short* Xq  = (unsigned short*)d_ws;  // converted query; reused as att
    unsigned short* Xk  = Xq + MD;
    unsigned short* Xv  = Xk + MD;
    unsigned short* Wqb = Xv + MD;
    unsigned short* Wkb = Wqb + WW;
    unsigned short* Wvb = Wkb + WW;
    unsigned short* Wob = Wvb + WW;
    unsigned short* Qp  = Wob + WW;
    unsigned short* Kp  = Qp + MD;
    unsigned short* Vt  = Kp + MD;           // V written transposed by the GEMM
    unsigned short* att = Xq;                // alias: Xq dead after QKV GEMM
    int* flags          = (int*)(Vt + MD);   // 2048 ints
    int* dflag          = flags + 2048;

    const dim3 blk(256);

    detect_dtype<<<1, 64, 0, stream>>>((const unsigned short*)query, dflag);

    cvt_all<<<dim3(2048, 7), blk, 0, stream>>>(
        (const float*)query, (const float*)key, (const float*)value,
        (const float*)wq, (const float*)wk, (const float*)wv, (const float*)wo,
        Xq, Xk, Xv, Wqb, Wkb, Wvb, Wob, dflag);
    mask_tiles<<<dim3(32, 32, 2), blk, 0, stream>>>(mask, flags);

    gemm_qkv<<<dim3(D_MOD / 128, Mtot / 64, 3), blk, 0, stream>>>(
        query, Xq, key, Xk, value, Xv,
        wq, Wqb, wk, Wkb, wv, Wvb,
        bq, bk, bv, Qp, Kp, Vt, dflag);

    flash_attn<<<dim3(T_SEQ / 128, 16, 2), blk, 0, stream>>>(Qp, Kp, Vt, mask, flags, att);

    gemm_out<<<dim3(D_MOD / 128, Mtot / 64), blk, 0, stream>>>(
        att, wo, Wob, bo, d_out, dflag);
}